// Round 1
// baseline (226.551 us; speedup 1.0000x reference)
//
#include <hip/hip_runtime.h>

#define Bn 256
#define Tn 512
#define Cn 256
#define Kn 8

typedef __attribute__((ext_vector_type(4))) float f32x4;

// v2: two timesteps per block, double-buffered fp8 LDS tiles.
//
// v1 (grid=512, one t/block): phase1 (HBM->fp8 LDS staging, ~21 us chip-wide,
// HBM-bound) and phase2 (MFMA+exp) ran back-to-back in ALL resident blocks
// simultaneously -> zero overlap, kernel ~= sum of phases (~51 us).
//
// v2: grid=256 (1 block/CU), 1024 threads = 16 waves (4/SIMD, same occupancy).
// Each block owns t0=2*bid, t1=t0+1. While phase2(t0) runs, staging of t1 is
// issued into Esh[1] at two sites between compute segments; wave TLP hides the
// staging latency. Expected: stage(t0) + max(stage(t1), compute(t0)) + compute(t1).
//
// Wave decomposition: rg = wave>>1 owns rows [32rg, 32rg+32); sh = wave&1 owns
// strips {2sh, 2sh+1} (64 cols each). The wave whose strips contain the
// diagonal strip sd=rg>>1 (i.e. sh == rg>>2) computes it first and publishes
// invn. Per-row num/den partials are reduced per wave, then the two
// strip-halves are summed via num_s/den_s[2][].
//
// LDS tile layout identical to v1: fp8 e4m3, paired-K swizzle — logical 8-byte
// half-unit b=kk*4+q (k-bytes [kk*32+q*8, +8)) stored at physical 16B unit
// u=(q*4+kp)^(row&7), half (kk&1), so one ds_read_b128 feeds MFMAs kk=2kp,2kp+1.
__global__ __launch_bounds__(1024, 4)
void tcon_k(const float* __restrict__ emb,
            const int* __restrict__ phon,
            const float* __restrict__ wts,
            float* __restrict__ out) {
    __shared__ __align__(16) unsigned char Esh[2][Bn * Bn];  // 2 x 64 KiB fp8
    __shared__ float invn[Bn];
    __shared__ int   pcls[2][Bn];
    __shared__ float num_s[2][Bn], den_s[2][Bn];
    __shared__ float csum[Kn];
    __shared__ int   ccnt[Kn];

    const int t0   = blockIdx.x * 2;
    const int t1   = t0 + 1;
    const int tid  = threadIdx.x;
    const int lane = tid & 63;
    const int wave = tid >> 6;        // 0..15
    const int rg   = wave >> 1;       // row group: rows [32rg, 32rg+32)
    const int sh   = wave & 1;        // strip half: strips {2sh, 2sh+1}
    const int i0   = rg * 32;
    const int sd   = rg >> 1;         // strip holding this row group's diagonal
    const bool own = ((rg >> 2) == sh);
    const int fs   = own ? sd : (sh << 1);              // first strip computed
    const int os   = own ? (sd ^ 1) : ((sh << 1) | 1);  // second strip

    const int q   = lane >> 4;
    const int l15 = lane & 15;
    const int e3  = l15 & 7;          // == row&7 for all our fragment rows

    if (tid < Kn) { csum[tid] = 0.0f; ccnt[tid] = 0; }
    if (tid < Bn) {
        pcls[0][tid] = phon[tid * Tn + t0];
        pcls[1][tid] = phon[tid * Tn + t1];
    }

    // ---- stage t0 into Esh[0] (256 B/thread) ----
    #pragma unroll 4
    for (int it = 0; it < 8; ++it) {
        const int f   = tid + it * 1024;
        const int row = f >> 5;
        const int b   = f & 31;                 // logical 8B half-unit
        const float4* p = (const float4*)(emb + ((size_t)row * Tn + t0) * Cn);
        const float4 v0 = p[2 * b];
        const float4 v1 = p[2 * b + 1];
        int lo = __builtin_amdgcn_cvt_pk_fp8_f32(v0.x, v0.y, 0, false);
        lo     = __builtin_amdgcn_cvt_pk_fp8_f32(v0.z, v0.w, lo, true);
        int hi = __builtin_amdgcn_cvt_pk_fp8_f32(v1.x, v1.y, 0, false);
        hi     = __builtin_amdgcn_cvt_pk_fp8_f32(v1.z, v1.w, hi, true);
        const int qq = b & 3, kk = b >> 2, kp = kk >> 1;
        const int ad = row * 256 + ((((qq << 2) + kp) ^ (row & 7)) << 4)
                     + ((kk & 1) << 3);
        int2 pk; pk.x = lo; pk.y = hi;
        *(int2*)&Esh[0][ad] = pk;
    }
    __syncthreads();

    f32x4 acc[2][4];

#define ZERO_ACC() do {                                                      \
    _Pragma("unroll") for (int _m = 0; _m < 2; ++_m)                         \
    _Pragma("unroll") for (int _n = 0; _n < 4; ++_n)                         \
        acc[_m][_n] = (f32x4){0.f, 0.f, 0.f, 0.f};                           \
} while (0)

// Stage 4 of the 8 per-thread units of t1 into Esh[1].
#define STAGE4(ITBASE) do {                                                  \
    _Pragma("unroll") for (int _it = (ITBASE); _it < (ITBASE) + 4; ++_it) {  \
        const int _f   = tid + _it * 1024;                                   \
        const int _row = _f >> 5;                                            \
        const int _b   = _f & 31;                                            \
        const float4* _p = (const float4*)(emb + ((size_t)_row * Tn + t1) * Cn); \
        const float4 _v0 = _p[2 * _b];                                       \
        const float4 _v1 = _p[2 * _b + 1];                                   \
        int _lo = __builtin_amdgcn_cvt_pk_fp8_f32(_v0.x, _v0.y, 0, false);   \
        _lo     = __builtin_amdgcn_cvt_pk_fp8_f32(_v0.z, _v0.w, _lo, true);  \
        int _hi = __builtin_amdgcn_cvt_pk_fp8_f32(_v1.x, _v1.y, 0, false);   \
        _hi     = __builtin_amdgcn_cvt_pk_fp8_f32(_v1.z, _v1.w, _hi, true);  \
        const int _qq = _b & 3, _kk = _b >> 2, _kp = _kk >> 1;               \
        const int _ad = _row * 256 + ((((_qq << 2) + _kp) ^ (_row & 7)) << 4)\
                      + ((_kk & 1) << 3);                                    \
        int2 _pk; _pk.x = _lo; _pk.y = _hi;                                  \
        *(int2*)&Esh[1][_ad] = _pk;                                          \
    }                                                                        \
} while (0)

// NOTE: expanded inside the (fully unrolled) tt loop; references `tt`.
#define COMPUTE_STRIP(JB) do {                                               \
    ZERO_ACC();                                                              \
    _Pragma("unroll") for (int kp = 0; kp < 4; ++kp) {                       \
        const int sw = (((q << 2) + kp) ^ e3) << 4;                          \
        ulonglong2 _a[2], _b[4];                                             \
        _Pragma("unroll") for (int _m = 0; _m < 2; ++_m)                     \
            _a[_m] = *(const ulonglong2*)&Esh[tt][(i0 + _m * 16 + l15) * 256 + sw]; \
        _Pragma("unroll") for (int _n = 0; _n < 4; ++_n)                     \
            _b[_n] = *(const ulonglong2*)&Esh[tt][((JB) + _n * 16 + l15) * 256 + sw]; \
        _Pragma("unroll") for (int _m = 0; _m < 2; ++_m)                     \
        _Pragma("unroll") for (int _n = 0; _n < 4; ++_n) {                   \
            acc[_m][_n] = __builtin_amdgcn_mfma_f32_16x16x32_fp8_fp8(        \
                (long)_a[_m].x, (long)_b[_n].x, acc[_m][_n], 0, 0, 0);       \
            acc[_m][_n] = __builtin_amdgcn_mfma_f32_16x16x32_fp8_fp8(        \
                (long)_a[_m].y, (long)_b[_n].y, acc[_m][_n], 0, 0, 0);       \
        }                                                                    \
    }                                                                        \
} while (0)

#define EPILOGUE(JB) do {                                                    \
    _Pragma("unroll") for (int _n = 0; _n < 4; ++_n) {                       \
        const int _j  = (JB) + _n * 16 + l15;                                \
        const int _pj = pcls[tt][_j];                                        \
        const float _ij = invn[_j];                                          \
        _Pragma("unroll") for (int _m = 0; _m < 2; ++_m)                     \
        _Pragma("unroll") for (int _r = 0; _r < 4; ++_r) {                   \
            const int _e = _m * 4 + _r;                                      \
            const int _ir = i0 + _m * 16 + q * 4 + _r;                       \
            const float _ex = __expf(acc[_m][_n][_r] * inv_i[_e] * _ij);     \
            const bool _nd = (_ir != _j);                                    \
            den_p[_e] += _nd ? _ex : 0.0f;                                   \
            num_p[_e] += (_nd && (_pj == pi[_e])) ? _ex : 0.0f;              \
        }                                                                    \
    }                                                                        \
} while (0)

    #pragma unroll
    for (int tt = 0; tt < 2; ++tt) {
        // ---- diagonal-first strip; owners publish norms ----
        COMPUTE_STRIP(fs * 64);
        if (own) {
            if ((rg & 1) == 0) {       // rows at strip offset 0..31 -> nj = mi
                #pragma unroll
                for (int r = 0; r < 4; ++r)
                    if (l15 == q * 4 + r) {
                        invn[i0 + l15]      = rsqrtf(fmaxf(acc[0][0][r], 1e-24f));
                        invn[i0 + 16 + l15] = rsqrtf(fmaxf(acc[1][1][r], 1e-24f));
                    }
            } else {                   // rows at strip offset 32..63 -> nj = 2+mi
                #pragma unroll
                for (int r = 0; r < 4; ++r)
                    if (l15 == q * 4 + r) {
                        invn[i0 + l15]      = rsqrtf(fmaxf(acc[0][2][r], 1e-24f));
                        invn[i0 + 16 + l15] = rsqrtf(fmaxf(acc[1][3][r], 1e-24f));
                    }
            }
        }
        if (tt == 0) STAGE4(0);        // t1 units 0..3 hide under barrier wait
        __syncthreads();               // invn published

        float num_p[8], den_p[8], inv_i[8];
        int   pi[8];
        #pragma unroll
        for (int e = 0; e < 8; ++e) {
            const int irow = i0 + (e >> 2) * 16 + q * 4 + (e & 3);
            num_p[e] = 0.0f; den_p[e] = 0.0f;
            pi[e]    = pcls[tt][irow];
            inv_i[e] = invn[irow];
        }

        EPILOGUE(fs * 64);             // consume held diagonal-strip acc
        if (tt == 0) STAGE4(4);        // t1 units 4..7 hide under 2nd strip
        COMPUTE_STRIP(os * 64);
        EPILOGUE(os * 64);

        // Reduce across the 16 l15 lanes of each quad -> per-half row sums.
        #pragma unroll
        for (int e = 0; e < 8; ++e) {
            float n = num_p[e], d = den_p[e];
            #pragma unroll
            for (int m = 1; m <= 8; m <<= 1) {
                n += __shfl_xor(n, m, 64);
                d += __shfl_xor(d, m, 64);
            }
            if (l15 == e) {
                const int irow = i0 + (e >> 2) * 16 + q * 4 + (e & 3);
                num_s[sh][irow] = n;
                den_s[sh][irow] = d;
            }
        }
        __syncthreads();               // both halves of num_s/den_s ready

        // ---- per-sample loss, class means ----
        if (tid < Bn) {
            const float nn = num_s[0][tid] + num_s[1][tid];
            const float dd = den_s[0][tid] + den_s[1][tid];
            const float ps = __logf(dd + 1e-6f) - __logf(nn);
            const int c = pcls[tt][tid];
            atomicAdd(&csum[c], ps);
            atomicAdd(&ccnt[c], 1);
        }
        __syncthreads();               // csum/ccnt complete

        if (tid == 0) {
            float accv = 0.0f; int np = 0;
            #pragma unroll
            for (int k = 0; k < Kn; ++k) {
                if (ccnt[k] > 0) { accv += (csum[k] / (float)ccnt[k]) * wts[k]; ++np; }
                csum[k] = 0.0f; ccnt[k] = 0;   // tid0-private reset for next t
            }
            atomicAdd(out, (accv / (float)np) * (1.0f / (float)Tn));
        }
        // No trailing barrier needed: tt=1 touches csum only after its own
        // barriers; invn/num_s rewrites are ordered by the barriers above.
    }
#undef ZERO_ACC
#undef STAGE4
#undef COMPUTE_STRIP
#undef EPILOGUE
}

extern "C" void kernel_launch(void* const* d_in, const int* in_sizes, int n_in,
                              void* d_out, int out_size, void* d_ws, size_t ws_size,
                              hipStream_t stream) {
    const float* emb  = (const float*)d_in[0];
    const int*   phon = (const int*)d_in[1];
    const float* wts  = (const float*)d_in[2];
    float*       out  = (float*)d_out;

    hipMemsetAsync(out, 0, sizeof(float), stream);
    tcon_k<<<Tn / 2, 1024, 0, stream>>>(emb, phon, wts, out);
}

// Round 2
// 220.643 us; speedup vs baseline: 1.0268x; 1.0268x over previous
//
#include <hip/hip_runtime.h>

#define Bn 256
#define Tn 512
#define Cn 256
#define Kn 8

typedef __attribute__((ext_vector_type(4))) float f32x4;

// v3: v2 structure (two timesteps/block, double-buffered fp8 LDS) with the
// register-spill fixed.
//
// v2 post-mortem: VGPR_Count=64 + WRITE_SIZE=43MB/dispatch = the allocator
// chased 8 waves/EU occupancy (launch_bounds 2nd arg is only a MINIMUM) and
// spilled ~42 VGPRs/thread to scratch; 88us kernel. LDS (135KiB) forces
// 1 block/CU = 4 waves/EU regardless, so cap the allocator there explicitly:
// amdgpu_waves_per_eu(4,4) -> 128-VGPR budget, no spill.
//
// Staging of t1 is split into 4 sites x 2 units (16B fp8 written/unit/thread)
// so at most 16 float-VGPRs of staged data are live at once, interleaved
// between compute segments of t0; 4 waves/SIMD TLP hides the HBM latency.
//
// Wave decomposition: rg = wave>>1 owns rows [32rg, 32rg+32); sh = wave&1 owns
// strips {2sh, 2sh+1} (64 cols each). The wave whose strips contain the
// diagonal strip sd=rg>>1 (i.e. sh == rg>>2) computes it first and publishes
// invn. Per-row num/den partials reduced per wave, strip-halves summed via
// num_s/den_s[2][].
//
// LDS tile layout: fp8 e4m3, paired-K swizzle — logical 8-byte half-unit
// b=kk*4+q (k-bytes [kk*32+q*8, +8)) stored at physical 16B unit
// u=(q*4+kp)^(row&7), half (kk&1), so one ds_read_b128 feeds MFMAs kk=2kp,2kp+1.
__global__ __launch_bounds__(1024)
__attribute__((amdgpu_waves_per_eu(4, 4)))
void tcon_k(const float* __restrict__ emb,
            const int* __restrict__ phon,
            const float* __restrict__ wts,
            float* __restrict__ out) {
    __shared__ __align__(16) unsigned char Esh[2][Bn * Bn];  // 2 x 64 KiB fp8
    __shared__ float invn[Bn];
    __shared__ int   pcls[2][Bn];
    __shared__ float num_s[2][Bn], den_s[2][Bn];
    __shared__ float csum[Kn];
    __shared__ int   ccnt[Kn];

    const int t0   = blockIdx.x * 2;
    const int t1   = t0 + 1;
    const int tid  = threadIdx.x;
    const int lane = tid & 63;
    const int wave = tid >> 6;        // 0..15
    const int rg   = wave >> 1;       // row group: rows [32rg, 32rg+32)
    const int sh   = wave & 1;        // strip half: strips {2sh, 2sh+1}
    const int i0   = rg * 32;
    const int sd   = rg >> 1;         // strip holding this row group's diagonal
    const bool own = ((rg >> 2) == sh);
    const int fs   = own ? sd : (sh << 1);              // first strip computed
    const int os   = own ? (sd ^ 1) : ((sh << 1) | 1);  // second strip

    const int q   = lane >> 4;
    const int l15 = lane & 15;
    const int e3  = l15 & 7;          // == row&7 for all our fragment rows

    if (tid < Kn) { csum[tid] = 0.0f; ccnt[tid] = 0; }
    if (tid < Bn) {
        pcls[0][tid] = phon[tid * Tn + t0];
        pcls[1][tid] = phon[tid * Tn + t1];
    }

    // ---- stage t0 into Esh[0] (256 B/thread) ----
    #pragma unroll 4
    for (int it = 0; it < 8; ++it) {
        const int f   = tid + it * 1024;
        const int row = f >> 5;
        const int b   = f & 31;                 // logical 8B half-unit
        const float4* p = (const float4*)(emb + ((size_t)row * Tn + t0) * Cn);
        const float4 v0 = p[2 * b];
        const float4 v1 = p[2 * b + 1];
        int lo = __builtin_amdgcn_cvt_pk_fp8_f32(v0.x, v0.y, 0, false);
        lo     = __builtin_amdgcn_cvt_pk_fp8_f32(v0.z, v0.w, lo, true);
        int hi = __builtin_amdgcn_cvt_pk_fp8_f32(v1.x, v1.y, 0, false);
        hi     = __builtin_amdgcn_cvt_pk_fp8_f32(v1.z, v1.w, hi, true);
        const int qq = b & 3, kk = b >> 2, kp = kk >> 1;
        const int ad = row * 256 + ((((qq << 2) + kp) ^ (row & 7)) << 4)
                     + ((kk & 1) << 3);
        int2 pk; pk.x = lo; pk.y = hi;
        *(int2*)&Esh[0][ad] = pk;
    }
    __syncthreads();

    f32x4 acc[2][4];

#define ZERO_ACC() do {                                                      \
    _Pragma("unroll") for (int _m = 0; _m < 2; ++_m)                         \
    _Pragma("unroll") for (int _n = 0; _n < 4; ++_n)                         \
        acc[_m][_n] = (f32x4){0.f, 0.f, 0.f, 0.f};                           \
} while (0)

// Stage 2 of the 8 per-thread units of t1 into Esh[1] (small live range).
#define STAGE2(ITBASE) do {                                                  \
    _Pragma("unroll") for (int _it = (ITBASE); _it < (ITBASE) + 2; ++_it) {  \
        const int _f   = tid + _it * 1024;                                   \
        const int _row = _f >> 5;                                            \
        const int _b   = _f & 31;                                            \
        const float4* _p = (const float4*)(emb + ((size_t)_row * Tn + t1) * Cn); \
        const float4 _v0 = _p[2 * _b];                                       \
        const float4 _v1 = _p[2 * _b + 1];                                   \
        int _lo = __builtin_amdgcn_cvt_pk_fp8_f32(_v0.x, _v0.y, 0, false);   \
        _lo     = __builtin_amdgcn_cvt_pk_fp8_f32(_v0.z, _v0.w, _lo, true);  \
        int _hi = __builtin_amdgcn_cvt_pk_fp8_f32(_v1.x, _v1.y, 0, false);   \
        _hi     = __builtin_amdgcn_cvt_pk_fp8_f32(_v1.z, _v1.w, _hi, true);  \
        const int _qq = _b & 3, _kk = _b >> 2, _kp = _kk >> 1;               \
        const int _ad = _row * 256 + ((((_qq << 2) + _kp) ^ (_row & 7)) << 4)\
                      + ((_kk & 1) << 3);                                    \
        int2 _pk; _pk.x = _lo; _pk.y = _hi;                                  \
        *(int2*)&Esh[1][_ad] = _pk;                                          \
    }                                                                        \
} while (0)

// NOTE: expanded inside the (fully unrolled) tt loop; references `tt`.
#define COMPUTE_STRIP(JB) do {                                               \
    ZERO_ACC();                                                              \
    _Pragma("unroll") for (int kp = 0; kp < 4; ++kp) {                       \
        const int sw = (((q << 2) + kp) ^ e3) << 4;                          \
        ulonglong2 _a[2], _b[4];                                             \
        _Pragma("unroll") for (int _m = 0; _m < 2; ++_m)                     \
            _a[_m] = *(const ulonglong2*)&Esh[tt][(i0 + _m * 16 + l15) * 256 + sw]; \
        _Pragma("unroll") for (int _n = 0; _n < 4; ++_n)                     \
            _b[_n] = *(const ulonglong2*)&Esh[tt][((JB) + _n * 16 + l15) * 256 + sw]; \
        _Pragma("unroll") for (int _m = 0; _m < 2; ++_m)                     \
        _Pragma("unroll") for (int _n = 0; _n < 4; ++_n) {                   \
            acc[_m][_n] = __builtin_amdgcn_mfma_f32_16x16x32_fp8_fp8(        \
                (long)_a[_m].x, (long)_b[_n].x, acc[_m][_n], 0, 0, 0);       \
            acc[_m][_n] = __builtin_amdgcn_mfma_f32_16x16x32_fp8_fp8(        \
                (long)_a[_m].y, (long)_b[_n].y, acc[_m][_n], 0, 0, 0);       \
        }                                                                    \
    }                                                                        \
} while (0)

#define EPILOGUE(JB) do {                                                    \
    _Pragma("unroll") for (int _n = 0; _n < 4; ++_n) {                       \
        const int _j  = (JB) + _n * 16 + l15;                                \
        const int _pj = pcls[tt][_j];                                        \
        const float _ij = invn[_j];                                          \
        _Pragma("unroll") for (int _m = 0; _m < 2; ++_m)                     \
        _Pragma("unroll") for (int _r = 0; _r < 4; ++_r) {                   \
            const int _e = _m * 4 + _r;                                      \
            const int _ir = i0 + _m * 16 + q * 4 + _r;                       \
            const float _ex = __expf(acc[_m][_n][_r] * inv_i[_e] * _ij);     \
            const bool _nd = (_ir != _j);                                    \
            den_p[_e] += _nd ? _ex : 0.0f;                                   \
            num_p[_e] += (_nd && (_pj == pi[_e])) ? _ex : 0.0f;              \
        }                                                                    \
    }                                                                        \
} while (0)

    #pragma unroll
    for (int tt = 0; tt < 2; ++tt) {
        if (tt == 0) STAGE2(0);        // t1 units 0..1: issue ASAP (HBM path)
        // ---- diagonal-first strip; owners publish norms ----
        COMPUTE_STRIP(fs * 64);
        if (own) {
            if ((rg & 1) == 0) {       // rows at strip offset 0..31 -> nj = mi
                #pragma unroll
                for (int r = 0; r < 4; ++r)
                    if (l15 == q * 4 + r) {
                        invn[i0 + l15]      = rsqrtf(fmaxf(acc[0][0][r], 1e-24f));
                        invn[i0 + 16 + l15] = rsqrtf(fmaxf(acc[1][1][r], 1e-24f));
                    }
            } else {                   // rows at strip offset 32..63 -> nj = 2+mi
                #pragma unroll
                for (int r = 0; r < 4; ++r)
                    if (l15 == q * 4 + r) {
                        invn[i0 + l15]      = rsqrtf(fmaxf(acc[0][2][r], 1e-24f));
                        invn[i0 + 16 + l15] = rsqrtf(fmaxf(acc[1][3][r], 1e-24f));
                    }
            }
        }
        if (tt == 0) STAGE2(2);        // t1 units 2..3 hide under barrier wait
        __syncthreads();               // invn published

        float num_p[8], den_p[8], inv_i[8];
        int   pi[8];
        #pragma unroll
        for (int e = 0; e < 8; ++e) {
            const int irow = i0 + (e >> 2) * 16 + q * 4 + (e & 3);
            num_p[e] = 0.0f; den_p[e] = 0.0f;
            pi[e]    = pcls[tt][irow];
            inv_i[e] = invn[irow];
        }

        EPILOGUE(fs * 64);             // consume held diagonal-strip acc
        if (tt == 0) STAGE2(4);        // t1 units 4..5 hide under 2nd strip
        COMPUTE_STRIP(os * 64);
        if (tt == 0) STAGE2(6);        // t1 units 6..7
        EPILOGUE(os * 64);

        // Reduce across the 16 l15 lanes of each quad -> per-half row sums.
        #pragma unroll
        for (int e = 0; e < 8; ++e) {
            float n = num_p[e], d = den_p[e];
            #pragma unroll
            for (int m = 1; m <= 8; m <<= 1) {
                n += __shfl_xor(n, m, 64);
                d += __shfl_xor(d, m, 64);
            }
            if (l15 == e) {
                const int irow = i0 + (e >> 2) * 16 + q * 4 + (e & 3);
                num_s[sh][irow] = n;
                den_s[sh][irow] = d;
            }
        }
        __syncthreads();               // both halves ready + Esh[1] complete

        // ---- per-sample loss, class means ----
        if (tid < Bn) {
            const float nn = num_s[0][tid] + num_s[1][tid];
            const float dd = den_s[0][tid] + den_s[1][tid];
            const float ps = __logf(dd + 1e-6f) - __logf(nn);
            const int c = pcls[tt][tid];
            atomicAdd(&csum[c], ps);
            atomicAdd(&ccnt[c], 1);
        }
        __syncthreads();               // csum/ccnt complete

        if (tid == 0) {
            float accv = 0.0f; int np = 0;
            #pragma unroll
            for (int k = 0; k < Kn; ++k) {
                if (ccnt[k] > 0) { accv += (csum[k] / (float)ccnt[k]) * wts[k]; ++np; }
                csum[k] = 0.0f; ccnt[k] = 0;   // tid0-private reset for next t
            }
            atomicAdd(out, (accv / (float)np) * (1.0f / (float)Tn));
        }
        // tt=1's invn/num_s writes are ordered behind this iteration's
        // barriers; csum atomics for tt=1 occur after tt=1's own barriers.
    }
#undef ZERO_ACC
#undef STAGE2
#undef COMPUTE_STRIP
#undef EPILOGUE
}

extern "C" void kernel_launch(void* const* d_in, const int* in_sizes, int n_in,
                              void* d_out, int out_size, void* d_ws, size_t ws_size,
                              hipStream_t stream) {
    const float* emb  = (const float*)d_in[0];
    const int*   phon = (const int*)d_in[1];
    const float* wts  = (const float*)d_in[2];
    float*       out  = (float*)d_out;

    hipMemsetAsync(out, 0, sizeof(float), stream);
    tcon_k<<<Tn / 2, 1024, 0, stream>>>(emb, phon, wts, out);
}

// Round 3
// 217.610 us; speedup vs baseline: 1.0411x; 1.0139x over previous
//
#include <hip/hip_runtime.h>

#define Bn 256
#define Tn 512
#define Cn 256
#define Kn 8

typedef __attribute__((ext_vector_type(4))) float f32x4;

// v4: v1's known-good compute geometry (512 thr = 8 waves, wave owns 32 rows,
// strips sd, sd^1, sd^2, sd^3) + two timesteps/block with double-buffered fp8
// LDS, and the v2/v3 register-spill killed two ways:
//  (a) 8 waves + 135 KiB LDS -> 1 block/CU -> 2 waves/EU -> 256-reg budget
//      (amdgpu_waves_per_eu(2,2) pins it). v2/v3 ran 16 waves at a 64-arch-reg
//      budget (accs split to AGPRs) and spilled 144 B/thread (WRITE_SIZE 37MB).
//  (b) every t1 staging site is fenced with sched_barrier(0) so its global
//      loads cannot be hoisted across compute -> max 32 staged regs live.
//
// Pipeline per block: stage(t0) ~ full-chip HBM burst; compute(t0) with 4
// interleaved staging sites for t1 (loads drain under the next strip's
// MFMA+LDS work); compute(t1) with no staging. Staging and compute now
// overlap chip-wide instead of phase-locking as in v1.
//
// LDS tile layout: fp8 e4m3, paired-K swizzle — logical 8-byte half-unit
// b=kk*4+q (k-bytes [kk*32+q*8, +8)) stored at physical 16B unit
// u=(q*4+kp)^(row&7), half (kk&1): one ds_read_b128 feeds MFMAs kk=2kp,2kp+1.
__global__ __launch_bounds__(512)
__attribute__((amdgpu_waves_per_eu(2, 2)))
void tcon_k(const float* __restrict__ emb,
            const int* __restrict__ phon,
            const float* __restrict__ wts,
            float* __restrict__ out) {
    __shared__ __align__(16) unsigned char Esh[2][Bn * Bn];  // 2 x 64 KiB fp8
    __shared__ float invn[Bn];
    __shared__ int   pcls[2][Bn];
    __shared__ float num_s[Bn], den_s[Bn];
    __shared__ float csum[Kn];
    __shared__ int   ccnt[Kn];

    const int t0   = blockIdx.x * 2;
    const int t1   = t0 + 1;
    const int tid  = threadIdx.x;
    const int lane = tid & 63;
    const int wave = tid >> 6;        // 0..7
    const int i0   = wave * 32;       // rows [i0, i0+32)
    const int sd   = wave >> 1;       // strip holding this wave's diagonal

    const int q   = lane >> 4;
    const int l15 = lane & 15;
    const int e3  = l15 & 7;          // == row&7 for all our fragment rows

    if (tid < Kn) { csum[tid] = 0.0f; ccnt[tid] = 0; }
    if (tid < Bn) {
        pcls[0][tid] = phon[tid * Tn + t0];
        pcls[1][tid] = phon[tid * Tn + t1];
    }

    // ---- stage t0 into Esh[0] (512 B fp32 -> 128 B fp8 per thread) ----
    #pragma unroll 4
    for (int it = 0; it < 16; ++it) {
        const int f   = tid + it * 512;
        const int row = f >> 5;
        const int b   = f & 31;                 // logical 8B half-unit
        const float4* p = (const float4*)(emb + ((size_t)row * Tn + t0) * Cn);
        const float4 v0 = p[2 * b];
        const float4 v1 = p[2 * b + 1];
        int lo = __builtin_amdgcn_cvt_pk_fp8_f32(v0.x, v0.y, 0, false);
        lo     = __builtin_amdgcn_cvt_pk_fp8_f32(v0.z, v0.w, lo, true);
        int hi = __builtin_amdgcn_cvt_pk_fp8_f32(v1.x, v1.y, 0, false);
        hi     = __builtin_amdgcn_cvt_pk_fp8_f32(v1.z, v1.w, hi, true);
        const int qq = b & 3, kk = b >> 2, kp = kk >> 1;
        const int ad = row * 256 + ((((qq << 2) + kp) ^ (row & 7)) << 4)
                     + ((kk & 1) << 3);
        int2 pk; pk.x = lo; pk.y = hi;
        *(int2*)&Esh[0][ad] = pk;
    }
    __syncthreads();

    f32x4 acc[2][4];

#define ZERO_ACC() do {                                                      \
    _Pragma("unroll") for (int _m = 0; _m < 2; ++_m)                         \
    _Pragma("unroll") for (int _n = 0; _n < 4; ++_n)                         \
        acc[_m][_n] = (f32x4){0.f, 0.f, 0.f, 0.f};                           \
} while (0)

// Stage 4 of the 16 per-thread units of t1 into Esh[1]; fenced so the loads
// cannot be hoisted across surrounding compute (live range = this site only).
#define STAGE4(ITBASE) do {                                                  \
    __builtin_amdgcn_sched_barrier(0);                                       \
    _Pragma("unroll") for (int _it = (ITBASE); _it < (ITBASE) + 4; ++_it) {  \
        const int _f   = tid + _it * 512;                                    \
        const int _row = _f >> 5;                                            \
        const int _b   = _f & 31;                                            \
        const float4* _p = (const float4*)(emb + ((size_t)_row * Tn + t1) * Cn); \
        const float4 _v0 = _p[2 * _b];                                       \
        const float4 _v1 = _p[2 * _b + 1];                                   \
        int _lo = __builtin_amdgcn_cvt_pk_fp8_f32(_v0.x, _v0.y, 0, false);   \
        _lo     = __builtin_amdgcn_cvt_pk_fp8_f32(_v0.z, _v0.w, _lo, true);  \
        int _hi = __builtin_amdgcn_cvt_pk_fp8_f32(_v1.x, _v1.y, 0, false);   \
        _hi     = __builtin_amdgcn_cvt_pk_fp8_f32(_v1.z, _v1.w, _hi, true);  \
        const int _qq = _b & 3, _kk = _b >> 2, _kp = _kk >> 1;               \
        const int _ad = _row * 256 + ((((_qq << 2) + _kp) ^ (_row & 7)) << 4)\
                      + ((_kk & 1) << 3);                                    \
        int2 _pk; _pk.x = _lo; _pk.y = _hi;                                  \
        *(int2*)&Esh[1][_ad] = _pk;                                          \
    }                                                                        \
    __builtin_amdgcn_sched_barrier(0);                                       \
} while (0)

// NOTE: expanded inside the (fully unrolled) tt loop; references `tt`.
#define COMPUTE_STRIP(JB) do {                                               \
    ZERO_ACC();                                                              \
    _Pragma("unroll") for (int kp = 0; kp < 4; ++kp) {                       \
        const int sw = (((q << 2) + kp) ^ e3) << 4;                          \
        ulonglong2 _a[2], _b[4];                                             \
        _Pragma("unroll") for (int _m = 0; _m < 2; ++_m)                     \
            _a[_m] = *(const ulonglong2*)&Esh[tt][(i0 + _m * 16 + l15) * 256 + sw]; \
        _Pragma("unroll") for (int _n = 0; _n < 4; ++_n)                     \
            _b[_n] = *(const ulonglong2*)&Esh[tt][((JB) + _n * 16 + l15) * 256 + sw]; \
        _Pragma("unroll") for (int _m = 0; _m < 2; ++_m)                     \
        _Pragma("unroll") for (int _n = 0; _n < 4; ++_n) {                   \
            acc[_m][_n] = __builtin_amdgcn_mfma_f32_16x16x32_fp8_fp8(        \
                (long)_a[_m].x, (long)_b[_n].x, acc[_m][_n], 0, 0, 0);       \
            acc[_m][_n] = __builtin_amdgcn_mfma_f32_16x16x32_fp8_fp8(        \
                (long)_a[_m].y, (long)_b[_n].y, acc[_m][_n], 0, 0, 0);       \
        }                                                                    \
    }                                                                        \
} while (0)

#define EPILOGUE(JB) do {                                                    \
    _Pragma("unroll") for (int _n = 0; _n < 4; ++_n) {                       \
        const int _j  = (JB) + _n * 16 + l15;                                \
        const int _pj = pcls[tt][_j];                                        \
        const float _ij = invn[_j];                                          \
        _Pragma("unroll") for (int _m = 0; _m < 2; ++_m)                     \
        _Pragma("unroll") for (int _r = 0; _r < 4; ++_r) {                   \
            const int _e = _m * 4 + _r;                                      \
            const int _ir = i0 + _m * 16 + q * 4 + _r;                       \
            const float _ex = __expf(acc[_m][_n][_r] * inv_i[_e] * _ij);     \
            const bool _nd = (_ir != _j);                                    \
            den_p[_e] += _nd ? _ex : 0.0f;                                   \
            num_p[_e] += (_nd && (_pj == pi[_e])) ? _ex : 0.0f;              \
        }                                                                    \
    }                                                                        \
} while (0)

    #pragma unroll
    for (int tt = 0; tt < 2; ++tt) {
        // ---- diagonal strip first; every wave publishes its 32 norms ----
        COMPUTE_STRIP(sd * 64);
        if ((wave & 1) == 0) {         // rows at strip offset 0..31 -> nj = mi
            #pragma unroll
            for (int r = 0; r < 4; ++r)
                if (l15 == q * 4 + r) {
                    invn[i0 + l15]      = rsqrtf(fmaxf(acc[0][0][r], 1e-24f));
                    invn[i0 + 16 + l15] = rsqrtf(fmaxf(acc[1][1][r], 1e-24f));
                }
        } else {                       // rows at strip offset 32..63 -> nj = 2+mi
            #pragma unroll
            for (int r = 0; r < 4; ++r)
                if (l15 == q * 4 + r) {
                    invn[i0 + l15]      = rsqrtf(fmaxf(acc[0][2][r], 1e-24f));
                    invn[i0 + 16 + l15] = rsqrtf(fmaxf(acc[1][3][r], 1e-24f));
                }
        }
        if (tt == 0) STAGE4(0);        // t1 units 0..3 hide under barrier wait
        __syncthreads();               // invn published

        float num_p[8], den_p[8], inv_i[8];
        int   pi[8];
        #pragma unroll
        for (int e = 0; e < 8; ++e) {
            const int irow = i0 + (e >> 2) * 16 + q * 4 + (e & 3);
            num_p[e] = 0.0f; den_p[e] = 0.0f;
            pi[e]    = pcls[tt][irow];
            inv_i[e] = invn[irow];
        }

        EPILOGUE(sd * 64);             // consume held diagonal-strip acc
        if (tt == 0) STAGE4(4);        // drains under next strip's MFMA+LDS
        COMPUTE_STRIP((sd ^ 1) * 64);
        EPILOGUE((sd ^ 1) * 64);
        if (tt == 0) STAGE4(8);
        COMPUTE_STRIP((sd ^ 2) * 64);
        EPILOGUE((sd ^ 2) * 64);
        if (tt == 0) STAGE4(12);
        COMPUTE_STRIP((sd ^ 3) * 64);
        EPILOGUE((sd ^ 3) * 64);

        // Reduce across the 16 l15 lanes of each quad; each row owned by 1 wave.
        #pragma unroll
        for (int e = 0; e < 8; ++e) {
            float n = num_p[e], d = den_p[e];
            #pragma unroll
            for (int m = 1; m <= 8; m <<= 1) {
                n += __shfl_xor(n, m, 64);
                d += __shfl_xor(d, m, 64);
            }
            if (l15 == e) {
                const int irow = i0 + (e >> 2) * 16 + q * 4 + (e & 3);
                num_s[irow] = n;
                den_s[irow] = d;
            }
        }
        __syncthreads();               // row sums ready; Esh[1] complete (tt=0)

        // ---- per-sample loss, class means ----
        if (tid < Bn) {
            const float ps = __logf(den_s[tid] + 1e-6f) - __logf(num_s[tid]);
            const int c = pcls[tt][tid];
            atomicAdd(&csum[c], ps);
            atomicAdd(&ccnt[c], 1);
        }
        __syncthreads();               // csum/ccnt complete

        if (tid == 0) {
            float accv = 0.0f; int np = 0;
            #pragma unroll
            for (int k = 0; k < Kn; ++k) {
                if (ccnt[k] > 0) { accv += (csum[k] / (float)ccnt[k]) * wts[k]; ++np; }
                csum[k] = 0.0f; ccnt[k] = 0;   // tid0-private reset for next t
            }
            atomicAdd(out, (accv / (float)np) * (1.0f / (float)Tn));
        }
        // tt=1's invn/num_s rewrites are ordered behind the barriers above;
        // tt=1's csum atomics occur only after tt=1's own two barriers.
    }
#undef ZERO_ACC
#undef STAGE4
#undef COMPUTE_STRIP
#undef EPILOGUE
}

extern "C" void kernel_launch(void* const* d_in, const int* in_sizes, int n_in,
                              void* d_out, int out_size, void* d_ws, size_t ws_size,
                              hipStream_t stream) {
    const float* emb  = (const float*)d_in[0];
    const int*   phon = (const int*)d_in[1];
    const float* wts  = (const float*)d_in[2];
    float*       out  = (float*)d_out;

    hipMemsetAsync(out, 0, sizeof(float), stream);
    tcon_k<<<Tn / 2, 512, 0, stream>>>(emb, phon, wts, out);
}

// Round 4
// 217.508 us; speedup vs baseline: 1.0416x; 1.0005x over previous
//
#include <hip/hip_runtime.h>

#define Bn 256
#define Tn 512
#define Cn 256
#define Kn 8

typedef __attribute__((ext_vector_type(4))) float f32x4;

// v5: kill the register spill by cutting DEMAND, not raising the budget.
//
// v2-v4 post-mortem: all three spilled exactly ~140 B/thread (WRITE_SIZE
// 17-43 MB) because COMPUTE_STRIP's fully-unrolled kp-loop keeps 24
// ulonglong2 fragments (48 VGPRs) in flight, + acc 32 + epilogue state 32 +
// staging 32 > budget. Latency of scratch round-trips (~900 cyc) inside the
// strip loop explains 82 us with NO pipe >16% busy.
//
// v5 changes (numerics identical):
//  - A-fragments loaded ONCE per tt into registers (8 ds_read_b128, 16 regs,
//    statically indexed a_[kp][m]) instead of re-read per strip.
//  - 32-col half-strips: acc[2][2] (AGPR), B in-flight 16 regs. Peak arch
//    VGPR demand ~110 < 128. Diagonal block is hs==wave -> uniform invn path.
//  - staging sites fenced with sched_barrier(0) as in v4 (32 regs, B dead).
//
// Geometry: 512 thr = 8 waves, wave owns rows [32w,32w+32), visits half-strips
// wave^k, k=0..7 (diagonal first -> invn). Two timesteps/block, double-buffered
// fp8 LDS (2x64 KiB) so t1 staging overlaps t0 compute.
//
// LDS tile layout: fp8 e4m3, paired-K swizzle — logical 8-byte half-unit
// b=kk*4+q (k-bytes [kk*32+q*8, +8)) stored at physical 16B unit
// u=(q*4+kp)^(row&7), half (kk&1): one ds_read_b128 feeds MFMAs kk=2kp,2kp+1.
__global__ __launch_bounds__(512)
__attribute__((amdgpu_waves_per_eu(2, 2)))
void tcon_k(const float* __restrict__ emb,
            const int* __restrict__ phon,
            const float* __restrict__ wts,
            float* __restrict__ out) {
    __shared__ __align__(16) unsigned char Esh[2][Bn * Bn];  // 2 x 64 KiB fp8
    __shared__ float invn[Bn];
    __shared__ int   pcls[2][Bn];
    __shared__ float num_s[Bn], den_s[Bn];
    __shared__ float csum[Kn];
    __shared__ int   ccnt[Kn];

    const int t0   = blockIdx.x * 2;
    const int t1   = t0 + 1;
    const int tid  = threadIdx.x;
    const int lane = tid & 63;
    const int wave = tid >> 6;        // 0..7
    const int i0   = wave * 32;       // rows [i0, i0+32)

    const int q   = lane >> 4;
    const int l15 = lane & 15;
    const int e3  = l15 & 7;          // == row&7 for all our fragment rows

    if (tid < Kn) { csum[tid] = 0.0f; ccnt[tid] = 0; }
    if (tid < Bn) {
        pcls[0][tid] = phon[tid * Tn + t0];
        pcls[1][tid] = phon[tid * Tn + t1];
    }

    // ---- stage t0 into Esh[0] (512 B fp32 -> 128 B fp8 per thread) ----
    #pragma unroll 4
    for (int it = 0; it < 16; ++it) {
        const int f   = tid + it * 512;
        const int row = f >> 5;
        const int b   = f & 31;                 // logical 8B half-unit
        const float4* p = (const float4*)(emb + ((size_t)row * Tn + t0) * Cn);
        const float4 v0 = p[2 * b];
        const float4 v1 = p[2 * b + 1];
        int lo = __builtin_amdgcn_cvt_pk_fp8_f32(v0.x, v0.y, 0, false);
        lo     = __builtin_amdgcn_cvt_pk_fp8_f32(v0.z, v0.w, lo, true);
        int hi = __builtin_amdgcn_cvt_pk_fp8_f32(v1.x, v1.y, 0, false);
        hi     = __builtin_amdgcn_cvt_pk_fp8_f32(v1.z, v1.w, hi, true);
        const int qq = b & 3, kk = b >> 2, kp = kk >> 1;
        const int ad = row * 256 + ((((qq << 2) + kp) ^ (row & 7)) << 4)
                     + ((kk & 1) << 3);
        int2 pk; pk.x = lo; pk.y = hi;
        *(int2*)&Esh[0][ad] = pk;
    }
    __syncthreads();

    f32x4 acc[2][2];

// Stage 4 of the 16 per-thread units of t1 into Esh[1]; fenced so the loads
// cannot be hoisted across surrounding compute (live range = this site only).
#define STAGE4(ITBASE) do {                                                  \
    __builtin_amdgcn_sched_barrier(0);                                       \
    _Pragma("unroll") for (int _it = (ITBASE); _it < (ITBASE) + 4; ++_it) {  \
        const int _f   = tid + _it * 512;                                    \
        const int _row = _f >> 5;                                            \
        const int _b   = _f & 31;                                            \
        const float4* _p = (const float4*)(emb + ((size_t)_row * Tn + t1) * Cn); \
        const float4 _v0 = _p[2 * _b];                                       \
        const float4 _v1 = _p[2 * _b + 1];                                   \
        int _lo = __builtin_amdgcn_cvt_pk_fp8_f32(_v0.x, _v0.y, 0, false);   \
        _lo     = __builtin_amdgcn_cvt_pk_fp8_f32(_v0.z, _v0.w, _lo, true);  \
        int _hi = __builtin_amdgcn_cvt_pk_fp8_f32(_v1.x, _v1.y, 0, false);   \
        _hi     = __builtin_amdgcn_cvt_pk_fp8_f32(_v1.z, _v1.w, _hi, true);  \
        const int _qq = _b & 3, _kk = _b >> 2, _kp = _kk >> 1;               \
        const int _ad = _row * 256 + ((((_qq << 2) + _kp) ^ (_row & 7)) << 4)\
                      + ((_kk & 1) << 3);                                    \
        int2 _pk; _pk.x = _lo; _pk.y = _hi;                                  \
        *(int2*)&Esh[1][_ad] = _pk;                                          \
    }                                                                        \
    __builtin_amdgcn_sched_barrier(0);                                       \
} while (0)

// 32-col half-strip: B in-flight = 8 ulonglong2 max; A from resident a_[][].
// NOTE: expanded inside the (fully unrolled) tt loop; references tt, a_, acc.
#define COMPUTE_HALF(JB) do {                                                \
    _Pragma("unroll") for (int _m = 0; _m < 2; ++_m)                         \
    _Pragma("unroll") for (int _n = 0; _n < 2; ++_n)                         \
        acc[_m][_n] = (f32x4){0.f, 0.f, 0.f, 0.f};                           \
    _Pragma("unroll") for (int _kp = 0; _kp < 4; ++_kp) {                    \
        const int _sw = (((q << 2) + _kp) ^ e3) << 4;                        \
        ulonglong2 _b[2];                                                    \
        _Pragma("unroll") for (int _n = 0; _n < 2; ++_n)                     \
            _b[_n] = *(const ulonglong2*)&Esh[tt][((JB) + _n * 16 + l15) * 256 + _sw]; \
        _Pragma("unroll") for (int _m = 0; _m < 2; ++_m)                     \
        _Pragma("unroll") for (int _n = 0; _n < 2; ++_n) {                   \
            acc[_m][_n] = __builtin_amdgcn_mfma_f32_16x16x32_fp8_fp8(        \
                (long)a_[_kp][_m].x, (long)_b[_n].x, acc[_m][_n], 0, 0, 0);  \
            acc[_m][_n] = __builtin_amdgcn_mfma_f32_16x16x32_fp8_fp8(        \
                (long)a_[_kp][_m].y, (long)_b[_n].y, acc[_m][_n], 0, 0, 0);  \
        }                                                                    \
    }                                                                        \
} while (0)

#define EPILOGUE(JB) do {                                                    \
    _Pragma("unroll") for (int _n = 0; _n < 2; ++_n) {                       \
        const int _j  = (JB) + _n * 16 + l15;                                \
        const int _pj = pcls[tt][_j];                                        \
        const float _ij = invn[_j];                                          \
        _Pragma("unroll") for (int _m = 0; _m < 2; ++_m)                     \
        _Pragma("unroll") for (int _r = 0; _r < 4; ++_r) {                   \
            const int _e = _m * 4 + _r;                                      \
            const int _ir = i0 + _m * 16 + q * 4 + _r;                       \
            const float _ex = __expf(acc[_m][_n][_r] * inv_i[_e] * _ij);     \
            const bool _nd = (_ir != _j);                                    \
            den_p[_e] += _nd ? _ex : 0.0f;                                   \
            num_p[_e] += (_nd && (_pj == pi[_e])) ? _ex : 0.0f;              \
        }                                                                    \
    }                                                                        \
} while (0)

    #pragma unroll
    for (int tt = 0; tt < 2; ++tt) {
        // ---- A fragments resident for this timestep (16 VGPRs) ----
        ulonglong2 a_[4][2];
        #pragma unroll
        for (int kp = 0; kp < 4; ++kp)
            #pragma unroll
            for (int m = 0; m < 2; ++m)
                a_[kp][m] = *(const ulonglong2*)
                    &Esh[tt][(i0 + m * 16 + l15) * 256 + ((((q << 2) + kp) ^ e3) << 4)];

        // ---- diagonal half-strip first; publish norms (uniform path) ----
        COMPUTE_HALF(i0);
        #pragma unroll
        for (int r = 0; r < 4; ++r)
            if (l15 == q * 4 + r) {
                invn[i0 + l15]      = rsqrtf(fmaxf(acc[0][0][r], 1e-24f));
                invn[i0 + 16 + l15] = rsqrtf(fmaxf(acc[1][1][r], 1e-24f));
            }
        if (tt == 0) STAGE4(0);        // t1 units 0..3 hide under barrier wait
        __syncthreads();               // invn published

        float num_p[8], den_p[8], inv_i[8];
        int   pi[8];
        #pragma unroll
        for (int e = 0; e < 8; ++e) {
            const int irow = i0 + (e >> 2) * 16 + q * 4 + (e & 3);
            num_p[e] = 0.0f; den_p[e] = 0.0f;
            pi[e]    = pcls[tt][irow];
            inv_i[e] = invn[irow];
        }

        EPILOGUE(i0);                  // consume held diagonal acc
        COMPUTE_HALF((wave ^ 1) * 32); EPILOGUE((wave ^ 1) * 32);
        if (tt == 0) STAGE4(4);        // drains under next half-strip's work
        COMPUTE_HALF((wave ^ 2) * 32); EPILOGUE((wave ^ 2) * 32);
        COMPUTE_HALF((wave ^ 3) * 32); EPILOGUE((wave ^ 3) * 32);
        if (tt == 0) STAGE4(8);
        COMPUTE_HALF((wave ^ 4) * 32); EPILOGUE((wave ^ 4) * 32);
        COMPUTE_HALF((wave ^ 5) * 32); EPILOGUE((wave ^ 5) * 32);
        if (tt == 0) STAGE4(12);
        COMPUTE_HALF((wave ^ 6) * 32); EPILOGUE((wave ^ 6) * 32);
        COMPUTE_HALF((wave ^ 7) * 32); EPILOGUE((wave ^ 7) * 32);

        // Reduce across the 16 l15 lanes of each quad; each row owned by 1 wave.
        #pragma unroll
        for (int e = 0; e < 8; ++e) {
            float n = num_p[e], d = den_p[e];
            #pragma unroll
            for (int m = 1; m <= 8; m <<= 1) {
                n += __shfl_xor(n, m, 64);
                d += __shfl_xor(d, m, 64);
            }
            if (l15 == e) {
                const int irow = i0 + (e >> 2) * 16 + q * 4 + (e & 3);
                num_s[irow] = n;
                den_s[irow] = d;
            }
        }
        __syncthreads();               // row sums ready; Esh[1] complete (tt=0)

        // ---- per-sample loss, class means ----
        if (tid < Bn) {
            const float ps = __logf(den_s[tid] + 1e-6f) - __logf(num_s[tid]);
            const int c = pcls[tt][tid];
            atomicAdd(&csum[c], ps);
            atomicAdd(&ccnt[c], 1);
        }
        __syncthreads();               // csum/ccnt complete

        if (tid == 0) {
            float accv = 0.0f; int np = 0;
            #pragma unroll
            for (int k = 0; k < Kn; ++k) {
                if (ccnt[k] > 0) { accv += (csum[k] / (float)ccnt[k]) * wts[k]; ++np; }
                csum[k] = 0.0f; ccnt[k] = 0;   // tid0-private reset for next t
            }
            atomicAdd(out, (accv / (float)np) * (1.0f / (float)Tn));
        }
        // tt=1's invn/num_s rewrites are ordered behind the barriers above;
        // tt=1's csum atomics occur only after tt=1's own two barriers.
    }
#undef STAGE4
#undef COMPUTE_HALF
#undef EPILOGUE
}

extern "C" void kernel_launch(void* const* d_in, const int* in_sizes, int n_in,
                              void* d_out, int out_size, void* d_ws, size_t ws_size,
                              hipStream_t stream) {
    const float* emb  = (const float*)d_in[0];
    const int*   phon = (const int*)d_in[1];
    const float* wts  = (const float*)d_in[2];
    float*       out  = (float*)d_out;

    hipMemsetAsync(out, 0, sizeof(float), stream);
    tcon_k<<<Tn / 2, 512, 0, stream>>>(emb, phon, wts, out);
}